// Round 2
// baseline (365.988 us; speedup 1.0000x reference)
//
#include <hip/hip_runtime.h>
#include <math.h>

// MoE router: B=4, T=4096, D=2048, E=64, K=2
//   logits = x @ gate_w^T  -> [16384, 64]; top-2; softmax over the 2 scores.
// Outputs flat: weights [16384*2] f32, then indices [16384*2] as float.
//
// R1 lesson: acc[] must be STATICALLY indexed (full unroll) or it lands in
// scratch (R0: VGPR=88, WRITE_SIZE=293MB of spill traffic, 316us).
// Layout: 8 waves = 4 D-slices x 2 expert-halves -> acc[32] per lane.

#define NTOK 16384
#define DDIM 2048
#define NEXP 64
#define TOK_PER_BLK 64
#define EPW 32      // experts per wave (expert half)
#define DCHUNK 512  // D elements per wave (D quarter)

__global__ __launch_bounds__(512) void moe_router_kernel(
    const float* __restrict__ x,      // [NTOK, DDIM]
    const float* __restrict__ gw,     // [NEXP, DDIM]
    float* __restrict__ out)          // [2*NTOK*2]
{
    // partials: [wave][local expert][token] = 8*32*64*4 = 64 KiB
    __shared__ float red[8][EPW][TOK_PER_BLK];
    // reduced logits: [expert][token] = 16 KiB  (total LDS 80 KiB -> 2 blk/CU)
    __shared__ float fin[NEXP][TOK_PER_BLK];

    const int tid  = threadIdx.x;
    const int lane = tid & 63;
    const int wav  = __builtin_amdgcn_readfirstlane(tid >> 6);
    const int eg   = wav & 1;     // expert half  (0/1)
    const int dsl  = wav >> 1;    // D slice      (0..3)
    const int tok0 = blockIdx.x * TOK_PER_BLK;
    const int dbase = dsl * DCHUNK;

    const float* xrow  = x  + (size_t)(tok0 + lane) * DDIM + dbase;
    const float* wbase = gw + (size_t)(eg * EPW) * DDIM + dbase;

    float acc[EPW];
#pragma unroll
    for (int e = 0; e < EPW; ++e) acc[e] = 0.f;

    // 32 iterations of 16-float sub-chunks; e-loop FULLY unrolled so every
    // acc[] access is compile-time static (registers, not scratch).
#pragma unroll 2
    for (int sc = 0; sc < DCHUNK; sc += 16) {
        float4 xv[4];
#pragma unroll
        for (int j = 0; j < 4; ++j)
            xv[j] = *reinterpret_cast<const float4*>(xrow + sc + j * 4);

#pragma unroll
        for (int e = 0; e < EPW; ++e) {
            const float4* wrow =
                reinterpret_cast<const float4*>(wbase + (size_t)e * DDIM + sc);
            float s = acc[e];
#pragma unroll
            for (int j = 0; j < 4; ++j) {
                float4 wv = wrow[j];   // wave-uniform address -> broadcast
                s = fmaf(xv[j].x, wv.x, s);
                s = fmaf(xv[j].y, wv.y, s);
                s = fmaf(xv[j].z, wv.z, s);
                s = fmaf(xv[j].w, wv.w, s);
            }
            acc[e] = s;
        }
    }

    // lanes consecutive -> conflict-free ds_write
#pragma unroll
    for (int e = 0; e < EPW; ++e) red[wav][e][lane] = acc[e];
    __syncthreads();

    // Reduce the 4 D-slices: 4096 (E,t) slots, 512 threads, 8 disjoint each.
    // wave index for (slice d, half g) is 2*d + g.
#pragma unroll
    for (int k = 0; k < 8; ++k) {
        int q  = tid + k * 512;
        int t  = q & 63;
        int E  = q >> 6;
        int g  = E >> 5;
        int el = E & 31;
        float s = red[0 + g][el][t]
                + red[2 + g][el][t]
                + red[4 + g][el][t]
                + red[6 + g][el][t];
        fin[E][t] = s;
    }
    __syncthreads();

    // Top-2 + softmax: lane t scans fin[e][t] (consecutive lanes -> no conflict)
    if (tid < TOK_PER_BLK) {
        const int t = tid;
        float m1 = -INFINITY, m2 = -INFINITY;
        int i1 = 0, i2 = 0;
#pragma unroll
        for (int e = 0; e < NEXP; ++e) {
            float v = fin[e][t];
            if (v > m1) {             // strict '>' keeps lowest index on ties
                m2 = m1; i2 = i1;
                m1 = v;  i1 = e;
            } else if (v > m2) {
                m2 = v;  i2 = e;
            }
        }
        float e2 = expf(m2 - m1);
        float denom = 1.f + e2;
        float w1 = 1.f / denom;
        float w2 = e2 / denom;

        const int gt = tok0 + t;
        out[gt * 2 + 0] = w1;
        out[gt * 2 + 1] = w2;
        out[NTOK * 2 + gt * 2 + 0] = (float)i1;
        out[NTOK * 2 + gt * 2 + 1] = (float)i2;
    }
}

extern "C" void kernel_launch(void* const* d_in, const int* in_sizes, int n_in,
                              void* d_out, int out_size, void* d_ws, size_t ws_size,
                              hipStream_t stream) {
    const float* x  = (const float*)d_in[0];   // [4,4096,2048] f32
    const float* gw = (const float*)d_in[1];   // [64,2048] f32
    float* out = (float*)d_out;

    dim3 grid(NTOK / TOK_PER_BLK);  // 256 blocks
    dim3 block(512);                // 8 waves
    moe_router_kernel<<<grid, block, 0, stream>>>(x, gw, out);
}